// Round 13
// baseline (163.229 us; speedup 1.0000x reference)
//
#include <hip/hip_runtime.h>

#define CH 256
#define NHEAD 4
#define HD 64
#define SP 4096
// softmax scale 1/8 with log2(e) folded in (we use exp2)
#define QSCALE 0.1803368801111204f

typedef __attribute__((ext_vector_type(8))) short bf16x8;   // MFMA A/B frag
typedef __attribute__((ext_vector_type(4))) float f32x4;    // MFMA C/D frag
typedef unsigned int u32;
typedef unsigned short u16;

__device__ inline u16 b16(float f) {
    u32 u = __float_as_uint(f);
    return (u16)((u + 0x8000u) >> 16);
}
__device__ inline u32 bpack(float lo, float hi) {
    u32 ul = __float_as_uint(lo), uh = __float_as_uint(hi);
    return ((uh + 0x8000u) & 0xffff0000u) | ((ul + 0x8000u) >> 16);
}
__device__ inline float fexp2(float x) { return __builtin_amdgcn_exp2f(x); }

// ---------------------------------------------------------------------------
// Kernel 1: GN partial sums + weight convert, 256 blocks.
// ---------------------------------------------------------------------------
__global__ __launch_bounds__(256) void prep_kernel(
    const float* __restrict__ x, float2* __restrict__ part,
    const float* __restrict__ wq, const float* __restrict__ wk,
    const float* __restrict__ wv, const float* __restrict__ wp,
    u16* __restrict__ wqb, u16* __restrict__ wkb,
    u16* __restrict__ wvb, u16* __restrict__ wpb)
{
    int tid = threadIdx.x;
    int bgq = blockIdx.x;            // (b*32+g)*4 + qtr
    int bg = bgq >> 2, qtr = bgq & 3;
    const float4* xp = (const float4*)(x + (size_t)bg * 8 * SP) + qtr * 2048;
    float s = 0.f, ss = 0.f;
    for (int i = tid; i < 2048; i += 256) {
        float4 u = xp[i];
        s  += (u.x + u.y) + (u.z + u.w);
        ss += (u.x * u.x + u.y * u.y) + (u.z * u.z + u.w * u.w);
    }
#pragma unroll
    for (int off = 32; off > 0; off >>= 1) {
        s  += __shfl_down(s, off);
        ss += __shfl_down(ss, off);
    }
    __shared__ float ws_s[4], ws_q[4];
    int w = tid >> 6;
    if ((tid & 63) == 0) { ws_s[w] = s; ws_q[w] = ss; }
    __syncthreads();
    if (tid == 0)
        part[bgq] = make_float2(ws_s[0] + ws_s[1] + ws_s[2] + ws_s[3],
                                ws_q[0] + ws_q[1] + ws_q[2] + ws_q[3]);

#pragma unroll
    for (int j = 0; j < 4; j++) {
        int idx = blockIdx.x * 1024 + j * 256 + tid;   // 0..262143
        int m = idx >> 16, i = idx & 65535;
        if (m == 0)      wqb[i] = b16(wq[i] * QSCALE);
        else if (m == 1) wkb[i] = b16(wk[i]);
        else if (m == 2) wvb[i] = b16(wv[i]);
        else {
            int c = i >> 8, col = i & 255;
            int n = col & 3, d = col >> 2;
            wpb[c * 256 + n * 64 + d] = b16(wp[i]);
        }
    }
}

// ---------------------------------------------------------------------------
// Kernel 2: Q/K/V projection, P-FUSED: one block per (b, 16-s-tile) stages the
// GN'd X tile ONCE, then runs 3 GEMMs (Q/K/V) against it. Grid (256,2) = 512
// blocks (2/CU, no tail). Outputs: Q bf16 [z][s][d]; K,V frag-packed.
// ---------------------------------------------------------------------------
__global__ __launch_bounds__(256) void qkv_gemm_kernel(
    const float* __restrict__ x, const float2* __restrict__ part,
    const float* __restrict__ gamma, const float* __restrict__ beta,
    const u16* __restrict__ wqb, const u16* __restrict__ wkb,
    const u16* __restrict__ wvb,
    const float* __restrict__ bq, const float* __restrict__ bk,
    const float* __restrict__ bv,
    u16* __restrict__ qt, u16* __restrict__ ktp, u16* __restrict__ vtp)
{
    int b = blockIdx.y;
    int s0 = blockIdx.x * 16;
    int tid = threadIdx.x, w = tid >> 6, lane = tid & 63;
    int t = lane >> 4, ln = lane & 15;

    __shared__ float As[256], Bs[256];
    __shared__ u16 Xs[16 * 264];    // GN'd X^T tile [s][c], 8.25 KB
    __shared__ u16 Ts[6144];        // epilogue staging (QK 4.5 KB / V 6 KB)

    // GN affine for channel tid
    {
        int c = tid, bg = b * 32 + (c >> 3);
        float s = 0.f, ss = 0.f;
#pragma unroll
        for (int q = 0; q < 4; q++) { float2 pp = part[bg * 4 + q]; s += pp.x; ss += pp.y; }
        float mu = s * (1.f / 32768.f);
        float var = ss * (1.f / 32768.f) - mu * mu;
        float rs = rsqrtf(var + 1e-5f);
        float ga = gamma[c];
        As[c] = rs * ga;
        Bs[c] = beta[c] - mu * rs * ga;
    }
    __syncthreads();

    // stage Xs[s][c] once: thread handles channel pair (cp, cp+1), 8 s-rows
    {
        int cp = (tid & 127) * 2, sh = (tid >> 7) * 8;
        const float* r0 = &x[((size_t)b * CH + cp) * SP + s0 + sh];
        const float* r1 = r0 + SP;
        float a0 = As[cp], b0 = Bs[cp], a1 = As[cp + 1], b1 = Bs[cp + 1];
#pragma unroll
        for (int j = 0; j < 2; j++) {
            float4 v0 = *(const float4*)&r0[4 * j];
            float4 v1 = *(const float4*)&r1[4 * j];
            int sb = sh + 4 * j;
            *(u32*)&Xs[(sb + 0) * 264 + cp] = bpack(fmaf(a0, v0.x, b0), fmaf(a1, v1.x, b1));
            *(u32*)&Xs[(sb + 1) * 264 + cp] = bpack(fmaf(a0, v0.y, b0), fmaf(a1, v1.y, b1));
            *(u32*)&Xs[(sb + 2) * 264 + cp] = bpack(fmaf(a0, v0.z, b0), fmaf(a1, v1.z, b1));
            *(u32*)&Xs[(sb + 3) * 264 + cp] = bpack(fmaf(a0, v0.w, b0), fmaf(a1, v1.w, b1));
        }
    }
    __syncthreads();

    const f32x4 z4 = {0.f, 0.f, 0.f, 0.f};

    // ===== GEMM + epilogue for each projection (X tile reused 3x) =====
#pragma unroll
    for (int p = 0; p < 3; p++) {
        const u16* W = (p == 0) ? wqb : (p == 1) ? wkb : wvb;
        const float* bias = (p == 0) ? bq : (p == 1) ? bk : bv;
        float bs = (p == 0) ? QSCALE : 1.f;

        f32x4 acc[4];
#pragma unroll
        for (int ks = 0; ks < 8; ks++) {
            bf16x8 af[4];
#pragma unroll
            for (int og = 0; og < 4; og++)
                af[og] = *(const bf16x8*)&W[(size_t)(w * 64 + og * 16 + ln) * CH + ks * 32 + t * 8];
            bf16x8 bfv = *(const bf16x8*)&Xs[ln * 264 + ks * 32 + t * 8];
#pragma unroll
            for (int og = 0; og < 4; og++)
                acc[og] = __builtin_amdgcn_mfma_f32_16x16x32_bf16(
                    af[og], bfv, (ks == 0) ? z4 : acc[og], 0, 0, 0);
        }

        // C rows o = w*64+og*16+4t+r (d = w*16+og*4+t, head n = r), col s = ln
        if (p < 2) {
#pragma unroll
            for (int og = 0; og < 4; og++)
#pragma unroll
                for (int r = 0; r < 4; r++) {
                    int o = w * 64 + og * 16 + 4 * t + r;
                    Ts[(r * 16 + ln) * 72 + (w * 16 + og * 4 + t)] =
                        b16(acc[og][r] + bias[o] * bs);
                }
            __syncthreads();
            if (p == 0) {
#pragma unroll
                for (int it = 0; it < 2; it++) {
                    int f = it * 256 + tid;
                    int o8 = f & 7, sl = (f >> 3) & 15, n = f >> 7;
                    *(uint4*)&qt[((size_t)(b * 4 + n) * SP + s0 + sl) * HD + o8 * 8] =
                        *(const uint4*)&Ts[(n * 16 + sl) * 72 + o8 * 8];
                }
            } else {
#pragma unroll
                for (int it = 0; it < 2; it++) {
                    int f = it * 256 + tid;
                    int o8 = f & 7, sl = (f >> 3) & 15, n = f >> 7;
                    int key = s0 + sl;
                    int g = ((key >> 4) & 3) * 2 + (o8 >> 2);
                    int lp = (key & 15) + 16 * (o8 & 3);
                    *(uint4*)&ktp[(size_t)(b * 4 + n) * SP * HD +
                                  (size_t)(key >> 6) * 4096 + g * 512 + lp * 8] =
                        *(const uint4*)&Ts[(n * 16 + sl) * 72 + o8 * 8];
                }
            }
            __syncthreads();   // Ts free for next p
        } else {
            // V: stage [n][d][s16] pitch 24, emit frag-packed
#pragma unroll
            for (int og = 0; og < 4; og++)
#pragma unroll
                for (int r = 0; r < 4; r++) {
                    int o = w * 64 + og * 16 + 4 * t + r;
                    Ts[(r * 64 + w * 16 + og * 4 + t) * 24 + ln] =
                        b16(acc[og][r] + bias[o]);
                }
            __syncthreads();
#pragma unroll
            for (int it = 0; it < 2; it++) {
                int f = it * 256 + tid;
                int so8 = f & 1, d = (f >> 1) & 63, n = f >> 7;
                int key = s0 + so8 * 8;
                int g = ((d >> 4) & 3) * 2 + ((key >> 5) & 1);
                int lp = (d & 15) + 16 * ((key >> 3) & 3);
                *(uint4*)&vtp[(size_t)(b * 4 + n) * SP * HD +
                              (size_t)(key >> 6) * 4096 + g * 512 + lp * 8] =
                    *(const uint4*)&Ts[(n * 64 + d) * 24 + so8 * 8];
            }
        }
    }
}

// ---------------------------------------------------------------------------
// Kernel 3: MFMA flash attention — R12 (q=64/wave, qg=4, two-key halves,
// no barriers, launch_bounds(256,2)). Unchanged: 44.3 µs proven.
// ---------------------------------------------------------------------------
template <int NT>
__global__ __launch_bounds__(256, 2) void attn_kernel(
    const u16* __restrict__ qtb, const u16* __restrict__ ktp,
    const u16* __restrict__ vtp, u16* __restrict__ opart,
    float* __restrict__ lpart)
{
    int bx = blockIdx.x;
    int z = bx & 7, qt_i = (bx >> 3) & 15, sp = bx >> 7;
    int sq0 = qt_i * 256;            // 256 q per block (64 per wave)
    int tile0 = sp * NT;
    const u16* qz = qtb + (size_t)z * SP * HD;
    const u16* kz = ktp + (size_t)z * SP * HD;
    const u16* vz = vtp + (size_t)z * SP * HD;

    int tid = threadIdx.x, w = tid >> 6, l = tid & 63;
    int t = l >> 4, ln = l & 15;

    __shared__ __align__(16) u32 Pb[4][4][256];   // [wave][qg][1 KB frag]

    bf16x8 qf[4][2];
#pragma unroll
    for (int qg = 0; qg < 4; qg++)
#pragma unroll
        for (int ds = 0; ds < 2; ds++)
            qf[qg][ds] = *(const bf16x8*)&qz[
                (size_t)(sq0 + w * 64 + qg * 16 + ln) * HD + ds * 32 + t * 8];

    bf16x8 kfA[4], kfB[4], vf[4];
#pragma unroll
    for (int i = 0; i < 4; i++)
        kfA[i] = *(const bf16x8*)&kz[(size_t)tile0 * 4096 + i * 512 + l * 8];

    float lsum[4] = {0.f, 0.f, 0.f, 0.f};
    f32x4 oacc[4][4];
#pragma unroll
    for (int qg = 0; qg < 4; qg++)
#pragma unroll
        for (int dg = 0; dg < 4; dg++)
            oacc[qg][dg] = (f32x4){0.f, 0.f, 0.f, 0.f};

    const f32x4 z4 = {0.f, 0.f, 0.f, 0.f};
    f32x4 sa[4][2];

    auto ep = [&](int qg) {
#pragma unroll
        for (int kg = 0; kg < 2; kg++) {
            float e0 = fexp2(sa[qg][kg][0]);
            float e1 = fexp2(sa[qg][kg][1]);
            float e2 = fexp2(sa[qg][kg][2]);
            float e3 = fexp2(sa[qg][kg][3]);
            lsum[qg] += (e0 + e1) + (e2 + e3);
            u32 p0 = __builtin_amdgcn_perm(__float_as_uint(e1), __float_as_uint(e0), 0x07060302u);
            u32 p1 = __builtin_amdgcn_perm(__float_as_uint(e3), __float_as_uint(e2), 0x07060302u);
            int Lt = ln + 16 * (kg * 2 + (t >> 1));
            *(uint2*)&Pb[w][qg][Lt * 4 + 2 * (t & 1)] = make_uint2(p0, p1);
        }
    };

#pragma unroll
    for (int kti = 0; kti < NT; kti++) {
        size_t tb = (size_t)(tile0 + kti) * 4096;

        // ---- half 0 (keys 0..31): V groups dg*2+0 ----
#pragma unroll
        for (int dg = 0; dg < 4; dg++)
            vf[dg] = *(const bf16x8*)&vz[tb + (dg * 2 + 0) * 512 + l * 8];
#pragma unroll
        for (int kg = 0; kg < 2; kg++)
#pragma unroll
            for (int qg = 0; qg < 4; qg++)
                sa[qg][kg] = __builtin_amdgcn_mfma_f32_16x16x32_bf16(
                    kfA[kg * 2 + 0], qf[qg][0], z4, 0, 0, 0);
#pragma unroll
        for (int kg = 0; kg < 2; kg++)
#pragma unroll
            for (int qg = 0; qg < 4; qg++)
                sa[qg][kg] = __builtin_amdgcn_mfma_f32_16x16x32_bf16(
                    kfA[kg * 2 + 1], qf[qg][1], sa[qg][kg], 0, 0, 0);
#pragma unroll
        for (int i = 0; i < 4; i++)
            kfB[i] = *(const bf16x8*)&kz[tb + (4 + i) * 512 + l * 8];
        ep(0);
#pragma unroll
        for (int qg = 0; qg < 4; qg++) {
            if (qg < 3) ep(qg + 1);
            bf16x8 pf = *(const bf16x8*)&Pb[w][qg][l * 4];
#pragma unroll
            for (int dg = 0; dg < 4; dg++)
                oacc[qg][dg] = __builtin_amdgcn_mfma_f32_16x16x32_bf16(
                    pf, vf[dg], oacc[qg][dg], 0, 0, 0);
        }

        // ---- half 1 (keys 32..63): V groups dg*2+1 ----
#pragma unroll
        for (int dg = 0; dg < 4; dg++)
            vf[dg] = *(const bf16x8*)&vz[tb + (dg * 2 + 1) * 512 + l * 8];
#pragma unroll
        for (int kg = 0; kg < 2; kg++)
#pragma unroll
            for (int qg = 0; qg < 4; qg++)
                sa[qg][kg] = __builtin_amdgcn_mfma_f32_16x16x32_bf16(
                    kfB[kg * 2 + 0], qf[qg][0], z4, 0, 0, 0);
#pragma unroll
        for (int kg = 0; kg < 2; kg++)
#pragma unroll
            for (int qg = 0; qg < 4; qg++)
                sa[qg][kg] = __builtin_amdgcn_mfma_f32_16x16x32_bf16(
                    kfB[kg * 2 + 1], qf[qg][1], sa[qg][kg], 0, 0, 0);
        if (kti < NT - 1) {
#pragma unroll
            for (int i = 0; i < 4; i++)
                kfA[i] = *(const bf16x8*)&kz[tb + 4096 + i * 512 + l * 8];
        }
        ep(0);
#pragma unroll
        for (int qg = 0; qg < 4; qg++) {
            if (qg < 3) ep(qg + 1);
            bf16x8 pf = *(const bf16x8*)&Pb[w][qg][l * 4];
#pragma unroll
            for (int dg = 0; dg < 4; dg++)
                oacc[qg][dg] = __builtin_amdgcn_mfma_f32_16x16x32_bf16(
                    pf, vf[dg], oacc[qg][dg], 0, 0, 0);
        }
    }

#pragma unroll
    for (int qg = 0; qg < 4; qg++) {
        lsum[qg] += __shfl_xor(lsum[qg], 16);
        lsum[qg] += __shfl_xor(lsum[qg], 32);
    }

    size_t obase = (size_t)(sp * 8 + z) * SP;
    u16* po = (u16*)&Pb[w][0][0];     // 4 KB = 32 q x 64 d
#pragma unroll
    for (int pass = 0; pass < 2; pass++) {
#pragma unroll
        for (int qh = 0; qh < 2; qh++) {
            int qg = pass * 2 + qh;
#pragma unroll
            for (int dg = 0; dg < 4; dg++)
#pragma unroll
                for (int r = 0; r < 4; r++)
                    po[(qh * 16 + 4 * t + r) * 64 + dg * 16 + ln] = b16(oacc[qg][dg][r]);
        }
#pragma unroll
        for (int i = 0; i < 4; i++) {
            int f = i * 512 + l * 8;
            int qloc = f >> 6, d0 = f & 63;
            uint4 v = *(const uint4*)&po[f];
            *(uint4*)&opart[(obase + sq0 + w * 64 + pass * 32 + qloc) * HD + d0] = v;
        }
    }
    if (t == 0)
#pragma unroll
        for (int qg = 0; qg < 4; qg++)
            lpart[obase + sq0 + w * 64 + qg * 16 + ln] = lsum[qg];
}

// ---------------------------------------------------------------------------
// Kernel 4: output projection + residual, C-SPLIT: grid (256,2,2) = 1024
// blocks (4/CU). Each block computes 128 output channels (og=2 per wave);
// k-split combine built cooperatively (duplicated per c-half).
// ---------------------------------------------------------------------------
template <int NSPLIT>
__global__ __launch_bounds__(256) void proj_gemm_kernel(
    const u16* __restrict__ opart, const float* __restrict__ lpart,
    const u16* __restrict__ wpb, const float* __restrict__ bp,
    const float* __restrict__ x, float* __restrict__ out)
{
    int b = blockIdx.y;
    int s0 = blockIdx.x * 16;
    int ch0 = blockIdx.z * 128;
    int tid = threadIdx.x, w = tid >> 6, lane = tid & 63;
    int t = lane >> 4, ln = lane & 15;

    __shared__ u16 BsL[16 * 264];

#pragma unroll
    for (int it = 0; it < 2; it++) {
        int f = it * 256 + tid;
        int oct = f & 31, s = f >> 5;
        int n = oct >> 3, d0 = (oct & 7) * 8;
        float lsumv = 0.f;
        float accv[8] = {0.f,0.f,0.f,0.f,0.f,0.f,0.f,0.f};
#pragma unroll
        for (int sp = 0; sp < NSPLIT; sp++) {
            size_t base = (size_t)(sp * 8 + b * 4 + n) * SP + s0 + s;
            lsumv += lpart[base];
            uint4 o4 = *(const uint4*)&opart[base * HD + d0];
            u32 ov[4] = {o4.x, o4.y, o4.z, o4.w};
#pragma unroll
            for (int i = 0; i < 4; i++) {
                accv[2 * i + 0] += __uint_as_float(ov[i] << 16);
                accv[2 * i + 1] += __uint_as_float(ov[i] & 0xffff0000u);
            }
        }
        float inv = 1.f / lsumv;
        u32 res[4];
#pragma unroll
        for (int i = 0; i < 4; i++)
            res[i] = bpack(accv[2 * i + 0] * inv, accv[2 * i + 1] * inv);
        *(uint4*)&BsL[s * 264 + oct * 8] = make_uint4(res[0], res[1], res[2], res[3]);
    }
    __syncthreads();

    f32x4 acc[2];
    const f32x4 z4 = {0.f, 0.f, 0.f, 0.f};
#pragma unroll
    for (int ks = 0; ks < 8; ks++) {
        bf16x8 af[2];
#pragma unroll
        for (int og = 0; og < 2; og++)
            af[og] = *(const bf16x8*)&wpb[(size_t)(ch0 + w * 32 + og * 16 + ln) * CH + ks * 32 + t * 8];
        bf16x8 bfv = *(const bf16x8*)&BsL[ln * 264 + ks * 32 + t * 8];
#pragma unroll
        for (int og = 0; og < 2; og++)
            acc[og] = __builtin_amdgcn_mfma_f32_16x16x32_bf16(
                af[og], bfv, (ks == 0) ? z4 : acc[og], 0, 0, 0);
    }

#pragma unroll
    for (int og = 0; og < 2; og++)
#pragma unroll
        for (int r = 0; r < 4; r++) {
            int c = ch0 + w * 32 + og * 16 + 4 * t + r;
            size_t idx = ((size_t)b * CH + c) * SP + s0 + ln;
            out[idx] = acc[og][r] + bp[c] + x[idx];
        }
}

// ---------------------------------------------------------------------------
extern "C" void kernel_launch(void* const* d_in, const int* in_sizes, int n_in,
                              void* d_out, int out_size, void* d_ws, size_t ws_size,
                              hipStream_t stream)
{
    const float* x     = (const float*)d_in[0];
    const float* gamma = (const float*)d_in[1];
    const float* beta  = (const float*)d_in[2];
    const float* wq = (const float*)d_in[3]; const float* bq = (const float*)d_in[4];
    const float* wk = (const float*)d_in[5]; const float* bk = (const float*)d_in[6];
    const float* wv = (const float*)d_in[7]; const float* bv = (const float*)d_in[8];
    const float* wp = (const float*)d_in[9]; const float* bp = (const float*)d_in[10];
    float* out = (float*)d_out;

    const size_t TEN = (size_t)8 * SP * HD;   // 2,097,152 elements
    const size_t NEED8 = 4096 + 524288 + 3 * TEN * 2 + 8 * TEN * 2 + 8 * 8 * SP * 4;
    int nsplit = (ws_size >= NEED8) ? 8 : 4;

    char* wsb = (char*)d_ws;
    float2* part = (float2*)wsb;              // 2 KB
    u16* wqb = (u16*)(wsb + 4096);
    u16* wkb = wqb + 65536;
    u16* wvb = wkb + 65536;
    u16* wpb = wvb + 65536;
    u16* qt  = wpb + 65536;
    u16* ktp = qt + TEN;
    u16* vtp = ktp + TEN;
    u16* opart = vtp + TEN;                   // nsplit x TEN
    float* lpart = (float*)(opart + (size_t)nsplit * TEN);

    prep_kernel<<<dim3(256), dim3(256), 0, stream>>>(
        x, part, wq, wk, wv, wp, wqb, wkb, wvb, wpb);
    qkv_gemm_kernel<<<dim3(256, 2), dim3(256), 0, stream>>>(
        x, part, gamma, beta, wqb, wkb, wvb, bq, bk, bv, qt, ktp, vtp);
    if (nsplit == 8) {
        attn_kernel<8><<<dim3(1024), dim3(256), 0, stream>>>(
            qt, ktp, vtp, opart, lpart);
        proj_gemm_kernel<8><<<dim3(256, 2, 2), dim3(256), 0, stream>>>(
            opart, lpart, wpb, bp, x, out);
    } else {
        attn_kernel<16><<<dim3(512), dim3(256), 0, stream>>>(
            qt, ktp, vtp, opart, lpart);
        proj_gemm_kernel<4><<<dim3(256, 2, 2), dim3(256), 0, stream>>>(
            opart, lpart, wpb, bp, x, out);
    }
}

// Round 14
// 149.985 us; speedup vs baseline: 1.0883x; 1.0883x over previous
//
#include <hip/hip_runtime.h>

#define CH 256
#define NHEAD 4
#define HD 64
#define SP 4096
// softmax scale 1/8 with log2(e) folded in (we use exp2)
#define QSCALE 0.1803368801111204f

typedef __attribute__((ext_vector_type(8))) short bf16x8;   // MFMA A/B frag
typedef __attribute__((ext_vector_type(4))) float f32x4;    // MFMA C/D frag
typedef unsigned int u32;
typedef unsigned short u16;

__device__ inline u16 b16(float f) {
    u32 u = __float_as_uint(f);
    return (u16)((u + 0x8000u) >> 16);
}
__device__ inline u32 bpack(float lo, float hi) {
    u32 ul = __float_as_uint(lo), uh = __float_as_uint(hi);
    return ((uh + 0x8000u) & 0xffff0000u) | ((ul + 0x8000u) >> 16);
}
__device__ inline float fexp2(float x) { return __builtin_amdgcn_exp2f(x); }

// ---------------------------------------------------------------------------
// Kernel 1: GN partial sums + weight convert, 1024 blocks (4/CU).
// part[bg*16 + chunk]: (b,g) x 16 spatial chunks of 512 float4.
// wconv: 1 element per thread across the whole grid.
// ---------------------------------------------------------------------------
__global__ __launch_bounds__(256) void prep_kernel(
    const float* __restrict__ x, float2* __restrict__ part,
    const float* __restrict__ wq, const float* __restrict__ wk,
    const float* __restrict__ wv, const float* __restrict__ wp,
    u16* __restrict__ wqb, u16* __restrict__ wkb,
    u16* __restrict__ wvb, u16* __restrict__ wpb)
{
    int tid = threadIdx.x;
    int bgq = blockIdx.x;            // (b*32+g)*16 + chunk
    int bg = bgq >> 4, chunk = bgq & 15;
    const float4* xp = (const float4*)(x + (size_t)bg * 8 * SP) + chunk * 512;
    float s = 0.f, ss = 0.f;
#pragma unroll
    for (int i = 0; i < 2; i++) {
        float4 u = xp[i * 256 + tid];
        s  += (u.x + u.y) + (u.z + u.w);
        ss += (u.x * u.x + u.y * u.y) + (u.z * u.z + u.w * u.w);
    }
#pragma unroll
    for (int off = 32; off > 0; off >>= 1) {
        s  += __shfl_down(s, off);
        ss += __shfl_down(ss, off);
    }
    __shared__ float ws_s[4], ws_q[4];
    int w = tid >> 6;
    if ((tid & 63) == 0) { ws_s[w] = s; ws_q[w] = ss; }
    __syncthreads();
    if (tid == 0)
        part[bgq] = make_float2(ws_s[0] + ws_s[1] + ws_s[2] + ws_s[3],
                                ws_q[0] + ws_q[1] + ws_q[2] + ws_q[3]);

    // weight conversion: 1 element per thread
    {
        int idx = blockIdx.x * 256 + tid;   // 0..262143
        int m = idx >> 16, i = idx & 65535;
        if (m == 0)      wqb[i] = b16(wq[i] * QSCALE);
        else if (m == 1) wkb[i] = b16(wk[i]);
        else if (m == 2) wvb[i] = b16(wv[i]);
        else {
            // coalesced read; permuted write: col d*4+n -> chan n*64+d
            int c = i >> 8, col = i & 255;
            int n = col & 3, d = col >> 2;
            wpb[c * 256 + n * 64 + d] = b16(wp[i]);
        }
    }
}

// ---------------------------------------------------------------------------
// Kernel 2: Q/K/V projection with GN fused (R12-proven: s-tile 32,
// grid (128,6) = 768 blocks). Outputs: Q bf16 [z][s][d]; K,V frag-packed
// ktp/vtp[z][tile64][g][lane][8].
// ---------------------------------------------------------------------------
__global__ __launch_bounds__(256) void qkv_gemm_kernel(
    const float* __restrict__ x, const float2* __restrict__ part,
    const float* __restrict__ gamma, const float* __restrict__ beta,
    const u16* __restrict__ wqb, const u16* __restrict__ wkb,
    const u16* __restrict__ wvb,
    const float* __restrict__ bq, const float* __restrict__ bk,
    const float* __restrict__ bv,
    u16* __restrict__ qt, u16* __restrict__ ktp, u16* __restrict__ vtp)
{
    int zz = blockIdx.y;            // b*3 + p
    int b = zz / 3, p = zz % 3;
    const u16* W = (p == 0) ? wqb : (p == 1) ? wkb : wvb;
    const float* bias = (p == 0) ? bq : (p == 1) ? bk : bv;
    float bs = (p == 0) ? QSCALE : 1.f;
    int s0 = blockIdx.x * 32;
    int tid = threadIdx.x, w = tid >> 6, lane = tid & 63;
    int t = lane >> 4, ln = lane & 15;

    __shared__ u16 SB[10240];       // X^T tile (32x264), later output staging
    __shared__ float As[256], Bs[256];

    // GN affine for channel tid (16 fine-grained partials per (b,g))
    {
        int c = tid, bg = b * 32 + (c >> 3);
        float s = 0.f, ss = 0.f;
#pragma unroll
        for (int q = 0; q < 16; q++) { float2 pp = part[bg * 16 + q]; s += pp.x; ss += pp.y; }
        float mu = s * (1.f / 32768.f);
        float var = ss * (1.f / 32768.f) - mu * mu;
        float rs = rsqrtf(var + 1e-5f);
        float ga = gamma[c];
        As[c] = rs * ga;
        Bs[c] = beta[c] - mu * rs * ga;
    }
    __syncthreads();

    // stage Xs[s][c] = bf16(a*x+b), pitch 264; channel-pair u32 DS writes
    {
        int c2 = (tid >> 3) * 2, sseg = (tid & 7) * 4;
#pragma unroll
        for (int it = 0; it < 4; it++) {
            int c = it * 64 + c2;
            float4 v0 = *(const float4*)&x[((size_t)b * CH + c) * SP + s0 + sseg];
            float4 v1 = *(const float4*)&x[((size_t)b * CH + c + 1) * SP + s0 + sseg];
            float a0 = As[c], b0 = Bs[c], a1 = As[c + 1], b1 = Bs[c + 1];
            float e0[4] = {fmaf(a0, v0.x, b0), fmaf(a0, v0.y, b0),
                           fmaf(a0, v0.z, b0), fmaf(a0, v0.w, b0)};
            float e1[4] = {fmaf(a1, v1.x, b1), fmaf(a1, v1.y, b1),
                           fmaf(a1, v1.z, b1), fmaf(a1, v1.w, b1)};
#pragma unroll
            for (int j = 0; j < 4; j++)
                *(u32*)&SB[(sseg + j) * 264 + c] = bpack(e0[j], e1[j]);
        }
    }
    __syncthreads();

    f32x4 acc[4][2];
#pragma unroll
    for (int og = 0; og < 4; og++)
#pragma unroll
        for (int sg = 0; sg < 2; sg++)
            acc[og][sg] = (f32x4){0.f, 0.f, 0.f, 0.f};

#pragma unroll
    for (int ks = 0; ks < 8; ks++) {
        bf16x8 af[4], bfv[2];
#pragma unroll
        for (int og = 0; og < 4; og++)
            af[og] = *(const bf16x8*)&W[(size_t)(w * 64 + og * 16 + ln) * CH + ks * 32 + t * 8];
#pragma unroll
        for (int sg = 0; sg < 2; sg++)
            bfv[sg] = *(const bf16x8*)&SB[(sg * 16 + ln) * 264 + ks * 32 + t * 8];
#pragma unroll
        for (int og = 0; og < 4; og++)
#pragma unroll
            for (int sg = 0; sg < 2; sg++)
                acc[og][sg] = __builtin_amdgcn_mfma_f32_16x16x32_bf16(
                    af[og], bfv[sg], acc[og][sg], 0, 0, 0);
    }
    __syncthreads();   // SB reused for output staging

    // C rows o = w*64+og*16+4t+r (d = w*16+og*4+t, head n = r), cols s = sg*16+ln
    if (p < 2) {
#pragma unroll
        for (int og = 0; og < 4; og++)
#pragma unroll
            for (int sg = 0; sg < 2; sg++)
#pragma unroll
                for (int r = 0; r < 4; r++) {
                    int o = w * 64 + og * 16 + 4 * t + r;
                    SB[(r * 32 + sg * 16 + ln) * 72 + (w * 16 + og * 4 + t)] =
                        b16(acc[og][sg][r] + bias[o] * bs);
                }
        __syncthreads();
        if (p == 0) {
#pragma unroll
            for (int it = 0; it < 4; it++) {
                int f = it * 256 + tid;
                int o8 = f & 7, sl = (f >> 3) & 31, n = f >> 8;
                *(uint4*)&qt[((size_t)(b * 4 + n) * SP + s0 + sl) * HD + o8 * 8] =
                    *(const uint4*)&SB[(n * 32 + sl) * 72 + o8 * 8];
            }
        } else {
#pragma unroll
            for (int it = 0; it < 4; it++) {
                int f = it * 256 + tid;
                int o8 = f & 7, sl = (f >> 3) & 31, n = f >> 8;
                int key = s0 + sl;
                int g = ((key >> 4) & 3) * 2 + (o8 >> 2);
                int lp = (key & 15) + 16 * (o8 & 3);
                *(uint4*)&ktp[(size_t)(b * 4 + n) * SP * HD +
                              (size_t)(key >> 6) * 4096 + g * 512 + lp * 8] =
                    *(const uint4*)&SB[(n * 32 + sl) * 72 + o8 * 8];
            }
        }
    } else {
#pragma unroll
        for (int og = 0; og < 4; og++)
#pragma unroll
            for (int sg = 0; sg < 2; sg++)
#pragma unroll
                for (int r = 0; r < 4; r++) {
                    int o = w * 64 + og * 16 + 4 * t + r;
                    SB[(r * 64 + w * 16 + og * 4 + t) * 40 + sg * 16 + ln] =
                        b16(acc[og][sg][r] + bias[o]);
                }
        __syncthreads();
#pragma unroll
        for (int it = 0; it < 4; it++) {
            int f = it * 256 + tid;
            int so8 = f & 3, d = (f >> 2) & 63, n = f >> 8;
            int key = s0 + so8 * 8;
            int g = ((d >> 4) & 3) * 2 + ((key >> 5) & 1);
            int lp = (d & 15) + 16 * ((key >> 3) & 3);
            *(uint4*)&vtp[(size_t)(b * 4 + n) * SP * HD +
                          (size_t)(key >> 6) * 4096 + g * 512 + lp * 8] =
                *(const uint4*)&SB[(n * 64 + d) * 40 + so8 * 8];
        }
    }
}

// ---------------------------------------------------------------------------
// Kernel 3: MFMA flash attention — R12 proven (q=64/wave, qg=4, two-key
// halves, no barriers, launch_bounds(256,2)). 44.3 µs.
// ---------------------------------------------------------------------------
template <int NT>
__global__ __launch_bounds__(256, 2) void attn_kernel(
    const u16* __restrict__ qtb, const u16* __restrict__ ktp,
    const u16* __restrict__ vtp, u16* __restrict__ opart,
    float* __restrict__ lpart)
{
    int bx = blockIdx.x;
    int z = bx & 7, qt_i = (bx >> 3) & 15, sp = bx >> 7;
    int sq0 = qt_i * 256;            // 256 q per block (64 per wave)
    int tile0 = sp * NT;
    const u16* qz = qtb + (size_t)z * SP * HD;
    const u16* kz = ktp + (size_t)z * SP * HD;
    const u16* vz = vtp + (size_t)z * SP * HD;

    int tid = threadIdx.x, w = tid >> 6, l = tid & 63;
    int t = l >> 4, ln = l & 15;

    __shared__ __align__(16) u32 Pb[4][4][256];   // [wave][qg][1 KB frag]

    bf16x8 qf[4][2];
#pragma unroll
    for (int qg = 0; qg < 4; qg++)
#pragma unroll
        for (int ds = 0; ds < 2; ds++)
            qf[qg][ds] = *(const bf16x8*)&qz[
                (size_t)(sq0 + w * 64 + qg * 16 + ln) * HD + ds * 32 + t * 8];

    bf16x8 kfA[4], kfB[4], vf[4];
#pragma unroll
    for (int i = 0; i < 4; i++)
        kfA[i] = *(const bf16x8*)&kz[(size_t)tile0 * 4096 + i * 512 + l * 8];

    float lsum[4] = {0.f, 0.f, 0.f, 0.f};
    f32x4 oacc[4][4];
#pragma unroll
    for (int qg = 0; qg < 4; qg++)
#pragma unroll
        for (int dg = 0; dg < 4; dg++)
            oacc[qg][dg] = (f32x4){0.f, 0.f, 0.f, 0.f};

    const f32x4 z4 = {0.f, 0.f, 0.f, 0.f};
    f32x4 sa[4][2];

    auto ep = [&](int qg) {
#pragma unroll
        for (int kg = 0; kg < 2; kg++) {
            float e0 = fexp2(sa[qg][kg][0]);
            float e1 = fexp2(sa[qg][kg][1]);
            float e2 = fexp2(sa[qg][kg][2]);
            float e3 = fexp2(sa[qg][kg][3]);
            lsum[qg] += (e0 + e1) + (e2 + e3);
            u32 p0 = __builtin_amdgcn_perm(__float_as_uint(e1), __float_as_uint(e0), 0x07060302u);
            u32 p1 = __builtin_amdgcn_perm(__float_as_uint(e3), __float_as_uint(e2), 0x07060302u);
            int Lt = ln + 16 * (kg * 2 + (t >> 1));
            *(uint2*)&Pb[w][qg][Lt * 4 + 2 * (t & 1)] = make_uint2(p0, p1);
        }
    };

#pragma unroll
    for (int kti = 0; kti < NT; kti++) {
        size_t tb = (size_t)(tile0 + kti) * 4096;

        // ---- half 0 (keys 0..31): V groups dg*2+0 ----
#pragma unroll
        for (int dg = 0; dg < 4; dg++)
            vf[dg] = *(const bf16x8*)&vz[tb + (dg * 2 + 0) * 512 + l * 8];
#pragma unroll
        for (int kg = 0; kg < 2; kg++)
#pragma unroll
            for (int qg = 0; qg < 4; qg++)
                sa[qg][kg] = __builtin_amdgcn_mfma_f32_16x16x32_bf16(
                    kfA[kg * 2 + 0], qf[qg][0], z4, 0, 0, 0);
#pragma unroll
        for (int kg = 0; kg < 2; kg++)
#pragma unroll
            for (int qg = 0; qg < 4; qg++)
                sa[qg][kg] = __builtin_amdgcn_mfma_f32_16x16x32_bf16(
                    kfA[kg * 2 + 1], qf[qg][1], sa[qg][kg], 0, 0, 0);
#pragma unroll
        for (int i = 0; i < 4; i++)
            kfB[i] = *(const bf16x8*)&kz[tb + (4 + i) * 512 + l * 8];
        ep(0);
#pragma unroll
        for (int qg = 0; qg < 4; qg++) {
            if (qg < 3) ep(qg + 1);
            bf16x8 pf = *(const bf16x8*)&Pb[w][qg][l * 4];
#pragma unroll
            for (int dg = 0; dg < 4; dg++)
                oacc[qg][dg] = __builtin_amdgcn_mfma_f32_16x16x32_bf16(
                    pf, vf[dg], oacc[qg][dg], 0, 0, 0);
        }

        // ---- half 1 (keys 32..63): V groups dg*2+1 ----
#pragma unroll
        for (int dg = 0; dg < 4; dg++)
            vf[dg] = *(const bf16x8*)&vz[tb + (dg * 2 + 1) * 512 + l * 8];
#pragma unroll
        for (int kg = 0; kg < 2; kg++)
#pragma unroll
            for (int qg = 0; qg < 4; qg++)
                sa[qg][kg] = __builtin_amdgcn_mfma_f32_16x16x32_bf16(
                    kfB[kg * 2 + 0], qf[qg][0], z4, 0, 0, 0);
#pragma unroll
        for (int kg = 0; kg < 2; kg++)
#pragma unroll
            for (int qg = 0; qg < 4; qg++)
                sa[qg][kg] = __builtin_amdgcn_mfma_f32_16x16x32_bf16(
                    kfB[kg * 2 + 1], qf[qg][1], sa[qg][kg], 0, 0, 0);
        if (kti < NT - 1) {
#pragma unroll
            for (int i = 0; i < 4; i++)
                kfA[i] = *(const bf16x8*)&kz[tb + 4096 + i * 512 + l * 8];
        }
        ep(0);
#pragma unroll
        for (int qg = 0; qg < 4; qg++) {
            if (qg < 3) ep(qg + 1);
            bf16x8 pf = *(const bf16x8*)&Pb[w][qg][l * 4];
#pragma unroll
            for (int dg = 0; dg < 4; dg++)
                oacc[qg][dg] = __builtin_amdgcn_mfma_f32_16x16x32_bf16(
                    pf, vf[dg], oacc[qg][dg], 0, 0, 0);
        }
    }

#pragma unroll
    for (int qg = 0; qg < 4; qg++) {
        lsum[qg] += __shfl_xor(lsum[qg], 16);
        lsum[qg] += __shfl_xor(lsum[qg], 32);
    }

    size_t obase = (size_t)(sp * 8 + z) * SP;
    u16* po = (u16*)&Pb[w][0][0];     // 4 KB = 32 q x 64 d
#pragma unroll
    for (int pass = 0; pass < 2; pass++) {
#pragma unroll
        for (int qh = 0; qh < 2; qh++) {
            int qg = pass * 2 + qh;
#pragma unroll
            for (int dg = 0; dg < 4; dg++)
#pragma unroll
                for (int r = 0; r < 4; r++)
                    po[(qh * 16 + 4 * t + r) * 64 + dg * 16 + ln] = b16(oacc[qg][dg][r]);
        }
#pragma unroll
        for (int i = 0; i < 4; i++) {
            int f = i * 512 + l * 8;
            int qloc = f >> 6, d0 = f & 63;
            uint4 v = *(const uint4*)&po[f];
            *(uint4*)&opart[(obase + sq0 + w * 64 + pass * 32 + qloc) * HD + d0] = v;
        }
    }
    if (t == 0)
#pragma unroll
        for (int qg = 0; qg < 4; qg++)
            lpart[obase + sq0 + w * 64 + qg * 16 + ln] = lsum[qg];
}

// ---------------------------------------------------------------------------
// Kernel 4: output projection + residual (R12-proven: full 256 channels per
// block, grid (256,2) = 512 blocks, NSPLIT compile-time).
// ---------------------------------------------------------------------------
template <int NSPLIT>
__global__ __launch_bounds__(256) void proj_gemm_kernel(
    const u16* __restrict__ opart, const float* __restrict__ lpart,
    const u16* __restrict__ wpb, const float* __restrict__ bp,
    const float* __restrict__ x, float* __restrict__ out)
{
    int b = blockIdx.y;
    int s0 = blockIdx.x * 16;
    int tid = threadIdx.x, w = tid >> 6, lane = tid & 63;
    int t = lane >> 4, ln = lane & 15;

    __shared__ u16 BsL[16 * 264];

#pragma unroll
    for (int it = 0; it < 2; it++) {
        int f = it * 256 + tid;
        int oct = f & 31, s = f >> 5;
        int n = oct >> 3, d0 = (oct & 7) * 8;
        float lsumv = 0.f;
        float accv[8] = {0.f,0.f,0.f,0.f,0.f,0.f,0.f,0.f};
#pragma unroll
        for (int sp = 0; sp < NSPLIT; sp++) {
            size_t base = (size_t)(sp * 8 + b * 4 + n) * SP + s0 + s;
            lsumv += lpart[base];
            uint4 o4 = *(const uint4*)&opart[base * HD + d0];
            u32 ov[4] = {o4.x, o4.y, o4.z, o4.w};
#pragma unroll
            for (int i = 0; i < 4; i++) {
                accv[2 * i + 0] += __uint_as_float(ov[i] << 16);
                accv[2 * i + 1] += __uint_as_float(ov[i] & 0xffff0000u);
            }
        }
        float inv = 1.f / lsumv;
        u32 res[4];
#pragma unroll
        for (int i = 0; i < 4; i++)
            res[i] = bpack(accv[2 * i + 0] * inv, accv[2 * i + 1] * inv);
        *(uint4*)&BsL[s * 264 + oct * 8] = make_uint4(res[0], res[1], res[2], res[3]);
    }
    __syncthreads();

    f32x4 acc[4];
#pragma unroll
    for (int og = 0; og < 4; og++)
        acc[og] = (f32x4){0.f, 0.f, 0.f, 0.f};

#pragma unroll
    for (int ks = 0; ks < 8; ks++) {
        bf16x8 af[4];
#pragma unroll
        for (int og = 0; og < 4; og++)
            af[og] = *(const bf16x8*)&wpb[(size_t)(w * 64 + og * 16 + ln) * CH + ks * 32 + t * 8];
        bf16x8 bfv = *(const bf16x8*)&BsL[ln * 264 + ks * 32 + t * 8];
#pragma unroll
        for (int og = 0; og < 4; og++)
            acc[og] = __builtin_amdgcn_mfma_f32_16x16x32_bf16(
                af[og], bfv, acc[og], 0, 0, 0);
    }

#pragma unroll
    for (int og = 0; og < 4; og++)
#pragma unroll
        for (int r = 0; r < 4; r++) {
            int c = w * 64 + og * 16 + 4 * t + r;
            size_t idx = ((size_t)b * CH + c) * SP + s0 + ln;
            out[idx] = acc[og][r] + bp[c] + x[idx];
        }
}

// ---------------------------------------------------------------------------
extern "C" void kernel_launch(void* const* d_in, const int* in_sizes, int n_in,
                              void* d_out, int out_size, void* d_ws, size_t ws_size,
                              hipStream_t stream)
{
    const float* x     = (const float*)d_in[0];
    const float* gamma = (const float*)d_in[1];
    const float* beta  = (const float*)d_in[2];
    const float* wq = (const float*)d_in[3]; const float* bq = (const float*)d_in[4];
    const float* wk = (const float*)d_in[5]; const float* bk = (const float*)d_in[6];
    const float* wv = (const float*)d_in[7]; const float* bv = (const float*)d_in[8];
    const float* wp = (const float*)d_in[9]; const float* bp = (const float*)d_in[10];
    float* out = (float*)d_out;

    const size_t TEN = (size_t)8 * SP * HD;   // 2,097,152 elements
    const size_t NEED8 = 16384 + 524288 + 3 * TEN * 2 + 8 * TEN * 2 + 8 * 8 * SP * 4;
    int nsplit = (ws_size >= NEED8) ? 8 : 4;

    char* wsb = (char*)d_ws;
    float2* part = (float2*)wsb;              // 1024 float2 = 8 KB
    u16* wqb = (u16*)(wsb + 16384);
    u16* wkb = wqb + 65536;
    u16* wvb = wkb + 65536;
    u16* wpb = wvb + 65536;
    u16* qt  = wpb + 65536;
    u16* ktp = qt + TEN;
    u16* vtp = ktp + TEN;
    u16* opart = vtp + TEN;                   // nsplit x TEN
    float* lpart = (float*)(opart + (size_t)nsplit * TEN);

    prep_kernel<<<dim3(1024), dim3(256), 0, stream>>>(
        x, part, wq, wk, wv, wp, wqb, wkb, wvb, wpb);
    qkv_gemm_kernel<<<dim3(128, 6), dim3(256), 0, stream>>>(
        x, part, gamma, beta, wqb, wkb, wvb, bq, bk, bv, qt, ktp, vtp);
    if (nsplit == 8) {
        attn_kernel<8><<<dim3(1024), dim3(256), 0, stream>>>(
            qt, ktp, vtp, opart, lpart);
        proj_gemm_kernel<8><<<dim3(256, 2), dim3(256), 0, stream>>>(
            opart, lpart, wpb, bp, x, out);
    } else {
        attn_kernel<16><<<dim3(512), dim3(256), 0, stream>>>(
            qt, ktp, vtp, opart, lpart);
        proj_gemm_kernel<4><<<dim3(256, 2), dim3(256), 0, stream>>>(
            opart, lpart, wpb, bp, x, out);
    }
}